// Round 1
// baseline (1123.018 us; speedup 1.0000x reference)
//
#include <hip/hip_runtime.h>
#include <stdint.h>

// ---------- types / helpers ----------
typedef __bf16 bf16x8 __attribute__((ext_vector_type(8)));
typedef float  f32x4  __attribute__((ext_vector_type(4)));

#define DEV __device__ __forceinline__

DEV unsigned short f2bf(float f) {
    unsigned int u = __float_as_uint(f);
    unsigned int r = (u + 0x7fffu + ((u >> 16) & 1u)) >> 16;   // RNE
    return (unsigned short)r;
}
DEV float bf2f(unsigned short s) {
    return __uint_as_float(((unsigned int)s) << 16);
}

// ---------- tiny fp32->bf16 convert ----------
__global__ __launch_bounds__(256) void cvt_kernel(const float* __restrict__ src,
                                                  unsigned short* __restrict__ dst, int n) {
    int i = blockIdx.x * blockDim.x + threadIdx.x;
    if (i < n) dst[i] = f2bf(src[i]);
}

// ---------- q = joint_queries @ wq^T + bq  (24 x 512, batch-invariant) ----------
__global__ __launch_bounds__(256) void qproj_kernel(const float* __restrict__ jq,
                                                    const float* __restrict__ ipw,
                                                    const float* __restrict__ ipb,
                                                    float* __restrict__ q) {
    __shared__ float zq[512];
    int j = blockIdx.x, t = threadIdx.x;
    zq[t] = jq[j * 512 + t];
    zq[t + 256] = jq[j * 512 + t + 256];
    __syncthreads();
    for (int c = t; c < 512; c += 256) {
        float acc = ipb[c];                         // bq
        const float* wr = ipw + (size_t)c * 512;    // wq rows 0..511
        for (int e = 0; e < 512; ++e) acc += zq[e] * wr[e];
        q[j * 512 + c] = acc;
    }
}

// ---------- qk_fold[hj][e] = (1/8) sum_d q[j][h*64+d] * wk[h*64+d][e] ; qb = (1/8) q.bk ----------
__global__ __launch_bounds__(256) void qkfold_kernel(const float* __restrict__ q,
                                                     const float* __restrict__ ipw,
                                                     const float* __restrict__ ipb,
                                                     unsigned short* __restrict__ qk,
                                                     float* __restrict__ qb) {
    int hj = blockIdx.x;                // hj = h*24 + j
    int h = hj / 24, j = hj - h * 24;
    int t = threadIdx.x;
    __shared__ float qh[64];
    if (t < 64) qh[t] = q[j * 512 + h * 64 + t];
    __syncthreads();
    for (int e = t; e < 512; e += 256) {
        float acc = 0.f;
        for (int d = 0; d < 64; ++d)
            acc += qh[d] * ipw[(size_t)(512 + h * 64 + d) * 512 + e];   // wk rows 512..1023
        qk[(size_t)hj * 512 + e] = f2bf(acc * 0.125f);
    }
    if (t == 0) {
        float acc = 0.f;
        for (int d = 0; d < 64; ++d) acc += qh[d] * ipb[512 + h * 64 + d];  // bk
        qb[hj] = acc * 0.125f;
    }
}

// ---------- generic MFMA GEMM: C(M,N) = A(M,K) @ B(N,K)^T + bias ----------
// A fp32 or bf16(ushort bits), B bf16 row-major (N,K), C fp32 or bf16.
// 64x64 tile, 256 threads = 4 waves, each wave one 16-row strip x 64 cols.
template <bool AF32, bool CBF16>
__global__ __launch_bounds__(256) void gemm_bt(const void* __restrict__ Aptr,
                                               const unsigned short* __restrict__ B,
                                               const float* __restrict__ bias,
                                               void* __restrict__ Cptr,
                                               int M, int N, int K) {
    __shared__ unsigned short As[64 * 40];   // 32 k + 8 pad per row (keeps 16B align, kills conflicts)
    __shared__ unsigned short Bs[64 * 40];

    const int tid  = threadIdx.x;
    const int wv   = tid >> 6;
    const int lane = tid & 63;
    const int m0 = blockIdx.y * 64, n0 = blockIdx.x * 64;
    const int r  = tid >> 2;          // 0..63 staging row
    const int kc = (tid & 3) * 8;     // 0,8,16,24 staging k-col

    f32x4 acc[4] = {{0.f,0.f,0.f,0.f},{0.f,0.f,0.f,0.f},{0.f,0.f,0.f,0.f},{0.f,0.f,0.f,0.f}};

    const int row16 = lane & 15;
    const int koff  = (lane >> 4) * 8;

    for (int kb = 0; kb < K; kb += 32) {
        // stage A tile (64 x 32)
        if constexpr (AF32) {
            const float* Af = (const float*)Aptr + (size_t)(m0 + r) * K + kb + kc;
            float4 f0 = *(const float4*)Af;
            float4 f1 = *(const float4*)(Af + 4);
            uint4 pk; unsigned short* ps = (unsigned short*)&pk;
            ps[0] = f2bf(f0.x); ps[1] = f2bf(f0.y); ps[2] = f2bf(f0.z); ps[3] = f2bf(f0.w);
            ps[4] = f2bf(f1.x); ps[5] = f2bf(f1.y); ps[6] = f2bf(f1.z); ps[7] = f2bf(f1.w);
            *(uint4*)&As[r * 40 + kc] = pk;
        } else {
            const unsigned short* Ab = (const unsigned short*)Aptr + (size_t)(m0 + r) * K + kb + kc;
            *(uint4*)&As[r * 40 + kc] = *(const uint4*)Ab;
        }
        // stage B tile (64 x 32)
        *(uint4*)&Bs[r * 40 + kc] = *(const uint4*)(B + (size_t)(n0 + r) * K + kb + kc);
        __syncthreads();

        // A frag: A[m=lane&15][k=(lane>>4)*8+j]
        bf16x8 af = *(const bf16x8*)&As[(wv * 16 + row16) * 40 + koff];
#pragma unroll
        for (int t = 0; t < 4; ++t) {
            // B operand: B[k][n] with n=lane&15, k=(lane>>4)*8+j  == Bs[n][k]
            bf16x8 bfr = *(const bf16x8*)&Bs[(t * 16 + row16) * 40 + koff];
            acc[t] = __builtin_amdgcn_mfma_f32_16x16x32_bf16(af, bfr, acc[t], 0, 0, 0);
        }
        __syncthreads();
    }

    // epilogue: C/D layout col=lane&15, row=(lane>>4)*4+reg
    const int cg = lane >> 4, col = lane & 15;
#pragma unroll
    for (int t = 0; t < 4; ++t) {
        int gn = n0 + t * 16 + col;
        float bv = bias ? bias[gn] : 0.f;
#pragma unroll
        for (int rr = 0; rr < 4; ++rr) {
            int gm = m0 + wv * 16 + cg * 4 + rr;
            float val = acc[t][rr] + bv;
            if constexpr (CBF16) ((unsigned short*)Cptr)[(size_t)gm * N + gn] = f2bf(val);
            else                 ((float*)Cptr)[(size_t)gm * N + gn] = val;
        }
    }
}

// ---------- attention: softmax over s, o = attn @ V, per (b,h) ----------
__global__ __launch_bounds__(256) void attn_kernel(const unsigned short* __restrict__ scores,
                                                   const unsigned short* __restrict__ V,
                                                   unsigned short* __restrict__ o) {
    const int b = blockIdx.x, h = blockIdx.y, tid = threadIdx.x;
    __shared__ float att[24][128];
    __shared__ unsigned short vt[128][72];

    for (int idx = tid; idx < 24 * 128; idx += 256) {
        int s = idx / 24, j = idx - s * 24;
        att[j][s] = bf2f(scores[((size_t)(b * 128 + s)) * 192 + h * 24 + j]);
    }
    for (int idx = tid; idx < 128 * 8; idx += 256) {
        int s = idx >> 3, c = idx & 7;
        *(uint4*)&vt[s][c * 8] = *(const uint4*)&V[((size_t)(b * 128 + s)) * 512 + h * 64 + c * 8];
    }
    __syncthreads();

    const int wv = tid >> 6, lane = tid & 63;
    for (int i = 0; i < 6; ++i) {
        int j = wv * 6 + i;
        float x0 = att[j][lane], x1 = att[j][lane + 64];
        float mx = fmaxf(x0, x1);
        for (int m = 32; m; m >>= 1) mx = fmaxf(mx, __shfl_xor(mx, m));
        float e0 = expf(x0 - mx), e1 = expf(x1 - mx);
        float sm = e0 + e1;
        for (int m = 32; m; m >>= 1) sm += __shfl_xor(sm, m);
        float inv = 1.f / sm;
        att[j][lane] = e0 * inv;
        att[j][lane + 64] = e1 * inv;
    }
    __syncthreads();

    const int d = tid & 63, jg = tid >> 6;
    for (int i = 0; i < 6; ++i) {
        int j = jg * 6 + i;
        float acc = 0.f;
#pragma unroll 4
        for (int s = 0; s < 128; ++s) acc += att[j][s] * bf2f(vt[s][d]);
        o[((size_t)b * 24 + j) * 512 + h * 64 + d] = f2bf(acc);
    }
}

// ---------- epilogue: LN + SiLU + w2 + normalize/softplus + kinematic chain ----------
__global__ __launch_bounds__(256) void head_kernel(const float* __restrict__ hmat,
                                                   const float* __restrict__ ln_g,
                                                   const float* __restrict__ ln_b,
                                                   const float* __restrict__ w2,
                                                   const float* __restrict__ b2,
                                                   const int* __restrict__ parent,
                                                   float* __restrict__ out) {
    const int b = blockIdx.x, tid = threadIdx.x, wv = tid >> 6, lane = tid & 63;
    __shared__ float offs[24][3];
    float* out_joints = out;
    float* out_off    = out + 73728;    // 1024*24*3
    float* out_len    = out + 147456;   // + 1024*24*3

    for (int batch = 0; batch < 6; ++batch) {
        int j = batch * 4 + wv;
        const float* hr = hmat + ((size_t)b * 24 + j) * 512 + lane * 8;
        float x[8];
        *(float4*)&x[0] = *(const float4*)hr;
        *(float4*)&x[4] = *(const float4*)(hr + 4);
        float s1 = 0.f, s2 = 0.f;
#pragma unroll
        for (int i2 = 0; i2 < 8; ++i2) { s1 += x[i2]; s2 += x[i2] * x[i2]; }
        for (int m = 32; m; m >>= 1) { s1 += __shfl_xor(s1, m); s2 += __shfl_xor(s2, m); }
        float mu   = s1 * (1.f / 512.f);
        float var  = s2 * (1.f / 512.f) - mu * mu;
        float rstd = rsqrtf(var + 1e-5f);

        float g[8], bb[8];
        *(float4*)&g[0]  = *(const float4*)(ln_g + lane * 8);
        *(float4*)&g[4]  = *(const float4*)(ln_g + lane * 8 + 4);
        *(float4*)&bb[0] = *(const float4*)(ln_b + lane * 8);
        *(float4*)&bb[4] = *(const float4*)(ln_b + lane * 8 + 4);

        float sv[8];
#pragma unroll
        for (int i2 = 0; i2 < 8; ++i2) {
            float y = (x[i2] - mu) * rstd * g[i2] + bb[i2];
            sv[i2] = y / (1.f + expf(-y));          // SiLU
        }
        float rsum[4];
#pragma unroll
        for (int c = 0; c < 4; ++c) {
            const float* wr = w2 + c * 512 + lane * 8;
            float w[8];
            *(float4*)&w[0] = *(const float4*)wr;
            *(float4*)&w[4] = *(const float4*)(wr + 4);
            float p = 0.f;
#pragma unroll
            for (int i2 = 0; i2 < 8; ++i2) p += sv[i2] * w[i2];
            rsum[c] = p;
        }
        for (int m = 32; m; m >>= 1) {
            rsum[0] += __shfl_xor(rsum[0], m);
            rsum[1] += __shfl_xor(rsum[1], m);
            rsum[2] += __shfl_xor(rsum[2], m);
            rsum[3] += __shfl_xor(rsum[3], m);
        }
        if (lane == 0) {
            if (j == 0) {
                offs[0][0] = offs[0][1] = offs[0][2] = 0.f;
                size_t ob = (size_t)b * 24 * 3;
                out_off[ob] = 0.f; out_off[ob + 1] = 0.f; out_off[ob + 2] = 0.f;
            } else {
                float d0 = rsum[0] + b2[0], d1 = rsum[1] + b2[1], d2 = rsum[2] + b2[2];
                float lr = rsum[3] + b2[3];
                float nrm = sqrtf(d0 * d0 + d1 * d1 + d2 * d2);
                float inv = 1.f / fmaxf(nrm, 1e-6f);
                float L = (lr > 0.f) ? lr + log1pf(expf(-lr)) : log1pf(expf(lr));  // softplus
                float o0 = d0 * inv * L, o1 = d1 * inv * L, o2 = d2 * inv * L;
                offs[j][0] = o0; offs[j][1] = o1; offs[j][2] = o2;
                size_t ob = ((size_t)b * 24 + j) * 3;
                out_off[ob] = o0; out_off[ob + 1] = o1; out_off[ob + 2] = o2;
                out_len[(size_t)b * 23 + j - 1] = L;
            }
        }
    }
    __syncthreads();
    if (tid < 3) {
        int d = tid;
        float cum[24]; cum[0] = 0.f;
        out_joints[(size_t)b * 24 * 3 + d] = 0.f;
        for (int j = 1; j < 24; ++j) {
            cum[j] = offs[j][d] + cum[parent[j]];
            out_joints[((size_t)b * 24 + j) * 3 + d] = cum[j];
        }
    }
}

// ---------- launch ----------
extern "C" void kernel_launch(void* const* d_in, const int* in_sizes, int n_in,
                              void* d_out, int out_size, void* d_ws, size_t ws_size,
                              hipStream_t stream) {
    const float* z    = (const float*)d_in[0];   // (1024,128,512)
    const float* jq   = (const float*)d_in[1];   // (1,24,512)
    const float* ipw  = (const float*)d_in[2];   // (1536,512)
    const float* ipb  = (const float*)d_in[3];   // (1536,)
    const float* opw  = (const float*)d_in[4];   // (512,512)
    const float* opb  = (const float*)d_in[5];
    const float* w1   = (const float*)d_in[6];   // (512,512)
    const float* b1   = (const float*)d_in[7];
    const float* lng  = (const float*)d_in[8];
    const float* lnb  = (const float*)d_in[9];
    const float* w2   = (const float*)d_in[10];  // (4,512)
    const float* b2   = (const float*)d_in[11];
    const int* parent = (const int*)d_in[12];
    float* out = (float*)d_out;

    char* ws = (char*)d_ws;
    size_t off = 0;
    auto alloc = [&](size_t bytes) {
        off = (off + 255) & ~(size_t)255;
        char* p = ws + off;
        off += bytes;
        return p;
    };

    float*          qf    = (float*)alloc((size_t)24 * 512 * 4);
    unsigned short* qk    = (unsigned short*)alloc((size_t)192 * 512 * 2);
    float*          qb    = (float*)alloc((size_t)192 * 4);
    unsigned short* wv_bf = (unsigned short*)alloc((size_t)512 * 512 * 2);
    unsigned short* op_bf = (unsigned short*)alloc((size_t)512 * 512 * 2);
    unsigned short* w1_bf = (unsigned short*)alloc((size_t)512 * 512 * 2);
    unsigned short* sc    = (unsigned short*)alloc((size_t)131072 * 192 * 2);
    unsigned short* Vb    = (unsigned short*)alloc((size_t)131072 * 512 * 2);
    unsigned short* ob    = (unsigned short*)alloc((size_t)24576 * 512 * 2);
    unsigned short* jfb   = (unsigned short*)alloc((size_t)24576 * 512 * 2);
    float*          hm    = (float*)alloc((size_t)24576 * 512 * 4);

    // weight converts (small)
    cvt_kernel<<<1024, 256, 0, stream>>>(ipw + (size_t)1024 * 512, wv_bf, 262144);
    cvt_kernel<<<1024, 256, 0, stream>>>(opw, op_bf, 262144);
    cvt_kernel<<<1024, 256, 0, stream>>>(w1, w1_bf, 262144);

    // q (24x512), then folded qk (192x512) + qb
    qproj_kernel<<<24, 256, 0, stream>>>(jq, ipw, ipb, qf);
    qkfold_kernel<<<192, 256, 0, stream>>>(qf, ipw, ipb, qk, qb);

    // scores = z @ qk^T + qb   (131072 x 192), bf16
    gemm_bt<true, true><<<dim3(3, 2048), 256, 0, stream>>>(z, qk, qb, sc, 131072, 192, 512);
    // V = z @ wv^T + bv        (131072 x 512), bf16
    gemm_bt<true, true><<<dim3(8, 2048), 256, 0, stream>>>(z, wv_bf, ipb + 1024, Vb, 131072, 512, 512);
    // softmax + attn@V -> o    (24576 x 512), bf16
    attn_kernel<<<dim3(1024, 8), 256, 0, stream>>>(sc, Vb, ob);
    // jf = o @ out_proj^T + opb
    gemm_bt<false, true><<<dim3(8, 384), 256, 0, stream>>>(ob, op_bf, opb, jfb, 24576, 512, 512);
    // h = jf @ w1^T + b1 (fp32 out for LN)
    gemm_bt<false, false><<<dim3(8, 384), 256, 0, stream>>>(jfb, w1_bf, b1, hm, 24576, 512, 512);
    // LN + SiLU + w2 + dir/len + chain
    head_kernel<<<1024, 256, 0, stream>>>(hm, lng, lnb, w2, b2, parent, out);
}

// Round 2
// 960.002 us; speedup vs baseline: 1.1698x; 1.1698x over previous
//
#include <hip/hip_runtime.h>
#include <stdint.h>

// ---------- types / helpers ----------
typedef __bf16 bf16x8 __attribute__((ext_vector_type(8)));
typedef float  f32x4  __attribute__((ext_vector_type(4)));

#define DEV __device__ __forceinline__

DEV unsigned short f2bf(float f) {
    unsigned int u = __float_as_uint(f);
    unsigned int r = (u + 0x7fffu + ((u >> 16) & 1u)) >> 16;   // RNE
    return (unsigned short)r;
}
DEV float bf2f(unsigned short s) {
    return __uint_as_float(((unsigned int)s) << 16);
}

typedef __attribute__((address_space(1))) const void gv_t;
typedef __attribute__((address_space(3))) void lv_t;
DEV void stage16(const unsigned short* g, unsigned short* l) {
    // async global->LDS DMA, 16B/lane, dest = wave-uniform base + lane*16
    __builtin_amdgcn_global_load_lds((gv_t*)g, (lv_t*)l, 16, 0, 0);
}

// ---------- vectorized fp32 -> bf16 (8 elements / thread) ----------
__global__ __launch_bounds__(256) void cvt8_kernel(const float* __restrict__ src,
                                                   unsigned short* __restrict__ dst, int n8) {
    int i = blockIdx.x * blockDim.x + threadIdx.x;
    if (i >= n8) return;
    const float4* s = (const float4*)(src + (size_t)i * 8);
    float4 x = s[0], y = s[1];
    uint4 pk; unsigned short* p = (unsigned short*)&pk;
    p[0]=f2bf(x.x); p[1]=f2bf(x.y); p[2]=f2bf(x.z); p[3]=f2bf(x.w);
    p[4]=f2bf(y.x); p[5]=f2bf(y.y); p[6]=f2bf(y.z); p[7]=f2bf(y.w);
    ((uint4*)dst)[i] = pk;
}

// ---------- q = joint_queries @ wq^T + bq  (24 x 512, batch-invariant) ----------
__global__ __launch_bounds__(256) void qproj_kernel(const float* __restrict__ jq,
                                                    const float* __restrict__ ipw,
                                                    const float* __restrict__ ipb,
                                                    float* __restrict__ q) {
    __shared__ float zq[512];
    int j = blockIdx.x, t = threadIdx.x;
    zq[t] = jq[j * 512 + t];
    zq[t + 256] = jq[j * 512 + t + 256];
    __syncthreads();
    for (int c = t; c < 512; c += 256) {
        float acc = ipb[c];
        const float* wr = ipw + (size_t)c * 512;
        for (int e = 0; e < 512; ++e) acc += zq[e] * wr[e];
        q[j * 512 + c] = acc;
    }
}

// ---------- qk_fold[hj][e] = (1/8) sum_d q[j][h*64+d]*wk[h*64+d][e] -> Bcat rows 0..191 ----------
__global__ __launch_bounds__(256) void qkfold_kernel(const float* __restrict__ q,
                                                     const float* __restrict__ ipw,
                                                     const float* __restrict__ ipb,
                                                     unsigned short* __restrict__ Bcat,
                                                     float* __restrict__ bias1) {
    int hj = blockIdx.x;                // hj = h*24 + j
    int h = hj / 24, j = hj - h * 24;
    int t = threadIdx.x;
    __shared__ float qh[64];
    if (t < 64) qh[t] = q[j * 512 + h * 64 + t];
    __syncthreads();
    for (int e = t; e < 512; e += 256) {
        float acc = 0.f;
        for (int d = 0; d < 64; ++d)
            acc += qh[d] * ipw[(size_t)(512 + h * 64 + d) * 512 + e];
        Bcat[(size_t)hj * 512 + e] = f2bf(acc * 0.125f);
    }
    if (t == 0) {
        float acc = 0.f;
        for (int d = 0; d < 64; ++d) acc += qh[d] * ipb[512 + h * 64 + d];
        bias1[hj] = acc * 0.125f;
    }
}

// ---------- pad: Bcat rows 704..767 = 0, bias1[192..767] ----------
__global__ __launch_bounds__(256) void pad_kernel(unsigned short* __restrict__ Bcat,
                                                  float* __restrict__ bias1,
                                                  const float* __restrict__ ipb) {
    int idx = blockIdx.x * 256 + threadIdx.x;
    if (idx < 32768) Bcat[(size_t)704 * 512 + idx] = 0;
    if (idx < 512) bias1[192 + idx] = ipb[1024 + idx];
    if (idx < 64) bias1[704 + idx] = 0.f;
}

// ---------- opT[j][k] = bf16(opw[k][j]) ----------
__global__ __launch_bounds__(256) void transp_kernel(const float* __restrict__ opw,
                                                     unsigned short* __restrict__ opT) {
    int j = blockIdx.x;
    for (int k = threadIdx.x; k < 512; k += 256)
        opT[(size_t)j * 512 + k] = f2bf(opw[(size_t)k * 512 + j]);
}

// ---------- bfold[i] = w1[i,:].opb + b1[i]  (fp32) ----------
__global__ __launch_bounds__(256) void bfold_kernel(const float* __restrict__ w1,
                                                    const float* __restrict__ opb,
                                                    const float* __restrict__ b1,
                                                    float* __restrict__ bfold) {
    __shared__ float ob[512];
    int t = threadIdx.x;
    ob[t] = opb[t]; ob[t + 256] = opb[t + 256];
    __syncthreads();
    int i = blockIdx.x * 256 + t;
    float acc = b1[i];
    const float* wr = w1 + (size_t)i * 512;
    for (int k = 0; k < 512; ++k) acc += wr[k] * ob[k];
    bfold[i] = acc;
}

// ---------- m97-structure GEMM: C(M,N)=A(M,K)@B(N,K)^T + bias, 128x128 tile, BK=32 ----------
// A,B bf16 (ushort bits). C bf16 or fp32 with leading dim ldc; store only cols < Nstore.
// Requires M%128==0, gridDim.x*128 <= Brows, K%32==0.
template <bool CBF16>
__global__ __launch_bounds__(256) void gemm128(const unsigned short* __restrict__ A,
                                               const unsigned short* __restrict__ B,
                                               const float* __restrict__ bias,
                                               void* __restrict__ Cptr,
                                               int K, int ldc, int Nstore) {
    __shared__ unsigned short As[4096];   // 128 x 32, row-major, unpadded (global_load_lds contiguity)
    __shared__ unsigned short Bs[4096];

    const int tid = threadIdx.x, wv = tid >> 6, lane = tid & 63;
    const int m0 = blockIdx.y << 7, n0 = blockIdx.x << 7;
    const int wr = wv >> 1, wc = wv & 1;

    // staging: wave wv stages chunks {2wv, 2wv+1} (16 rows x 32 k each) of A and B
    const int srow = lane >> 2;            // 0..15
    const int scol = (lane & 3) << 3;      // 0,8,16,24
    const int c0 = wv << 1;
    const unsigned short* pA = A + (size_t)(m0 + c0 * 16 + srow) * K + scol;
    const unsigned short* pB = B + (size_t)(n0 + c0 * 16 + srow) * K + scol;
    unsigned short* lA = As + (c0 << 9);
    unsigned short* lB = Bs + (c0 << 9);
    const size_t rowStep = (size_t)16 * K;

    f32x4 acc[4][4];
#pragma unroll
    for (int i = 0; i < 4; ++i)
#pragma unroll
        for (int j = 0; j < 4; ++j) acc[i][j] = f32x4{0.f, 0.f, 0.f, 0.f};

    const int row16 = lane & 15, kg8 = (lane >> 4) << 3;
    const int aoff = ((wr << 6) + row16) * 32 + kg8;
    const int boff = ((wc << 6) + row16) * 32 + kg8;

    for (int kb = 0; kb < K; kb += 32) {
        stage16(pA + kb, lA);
        stage16(pA + rowStep + kb, lA + 512);
        stage16(pB + kb, lB);
        stage16(pB + rowStep + kb, lB + 512);
        __syncthreads();   // compiler emits vmcnt(0) drain before barrier

        bf16x8 a[4], b[4];
#pragma unroll
        for (int i = 0; i < 4; ++i) a[i] = *(const bf16x8*)&As[aoff + (i << 9)];
#pragma unroll
        for (int j = 0; j < 4; ++j) b[j] = *(const bf16x8*)&Bs[boff + (j << 9)];
#pragma unroll
        for (int i = 0; i < 4; ++i)
#pragma unroll
            for (int j = 0; j < 4; ++j)
                acc[i][j] = __builtin_amdgcn_mfma_f32_16x16x32_bf16(a[i], b[j], acc[i][j], 0, 0, 0);
        __syncthreads();
    }

    // epilogue: C/D layout col=lane&15, row=(lane>>4)*4+reg
    const int cg = lane >> 4, col = lane & 15;
#pragma unroll
    for (int j = 0; j < 4; ++j) {
        int gn = n0 + (wc << 6) + (j << 4) + col;
        if (gn >= Nstore) continue;
        float bv = bias ? bias[gn] : 0.f;
#pragma unroll
        for (int i = 0; i < 4; ++i) {
            int gmb = m0 + (wr << 6) + (i << 4) + (cg << 2);
#pragma unroll
            for (int rr = 0; rr < 4; ++rr) {
                float val = acc[i][j][rr] + bv;
                if constexpr (CBF16)
                    ((unsigned short*)Cptr)[(size_t)(gmb + rr) * ldc + gn] = f2bf(val);
                else
                    ((float*)Cptr)[(size_t)(gmb + rr) * ldc + gn] = val;
            }
        }
    }
}

// ---------- attention: softmax over s, o = attn @ V, per (b,h); reads fused scV (ld=704) ----------
__global__ __launch_bounds__(256) void attn_kernel(const unsigned short* __restrict__ scV,
                                                   unsigned short* __restrict__ o) {
    const int b = blockIdx.x, h = blockIdx.y, tid = threadIdx.x;
    __shared__ float att[24][128];
    __shared__ unsigned short vt[128][72];

    for (int idx = tid; idx < 24 * 128; idx += 256) {
        int s = idx / 24, j = idx - s * 24;
        att[j][s] = bf2f(scV[((size_t)(b * 128 + s)) * 704 + h * 24 + j]);
    }
    for (int idx = tid; idx < 128 * 8; idx += 256) {
        int s = idx >> 3, c = idx & 7;
        *(uint4*)&vt[s][c * 8] =
            *(const uint4*)&scV[((size_t)(b * 128 + s)) * 704 + 192 + h * 64 + c * 8];
    }
    __syncthreads();

    const int wv = tid >> 6, lane = tid & 63;
    for (int i = 0; i < 6; ++i) {
        int j = wv * 6 + i;
        float x0 = att[j][lane], x1 = att[j][lane + 64];
        float mx = fmaxf(x0, x1);
        for (int m = 32; m; m >>= 1) mx = fmaxf(mx, __shfl_xor(mx, m));
        float e0 = expf(x0 - mx), e1 = expf(x1 - mx);
        float sm = e0 + e1;
        for (int m = 32; m; m >>= 1) sm += __shfl_xor(sm, m);
        float inv = 1.f / sm;
        att[j][lane] = e0 * inv;
        att[j][lane + 64] = e1 * inv;
    }
    __syncthreads();

    const int d = tid & 63, jg = tid >> 6;
    for (int i = 0; i < 6; ++i) {
        int j = jg * 6 + i;
        float acc = 0.f;
#pragma unroll 4
        for (int s = 0; s < 128; ++s) acc += att[j][s] * bf2f(vt[s][d]);
        o[((size_t)b * 24 + j) * 512 + h * 64 + d] = f2bf(acc);
    }
}

// ---------- epilogue: LN + SiLU + w2 + normalize/softplus + kinematic chain ----------
__global__ __launch_bounds__(256) void head_kernel(const float* __restrict__ hmat,
                                                   const float* __restrict__ ln_g,
                                                   const float* __restrict__ ln_b,
                                                   const float* __restrict__ w2,
                                                   const float* __restrict__ b2,
                                                   const int* __restrict__ parent,
                                                   float* __restrict__ out) {
    const int b = blockIdx.x, tid = threadIdx.x, wv = tid >> 6, lane = tid & 63;
    __shared__ float offs[24][3];
    float* out_joints = out;
    float* out_off    = out + 73728;    // 1024*24*3
    float* out_len    = out + 147456;   // + 1024*24*3

    for (int batch = 0; batch < 6; ++batch) {
        int j = batch * 4 + wv;
        const float* hr = hmat + ((size_t)b * 24 + j) * 512 + lane * 8;
        float x[8];
        *(float4*)&x[0] = *(const float4*)hr;
        *(float4*)&x[4] = *(const float4*)(hr + 4);
        float s1 = 0.f, s2 = 0.f;
#pragma unroll
        for (int i2 = 0; i2 < 8; ++i2) { s1 += x[i2]; s2 += x[i2] * x[i2]; }
        for (int m = 32; m; m >>= 1) { s1 += __shfl_xor(s1, m); s2 += __shfl_xor(s2, m); }
        float mu   = s1 * (1.f / 512.f);
        float var  = s2 * (1.f / 512.f) - mu * mu;
        float rstd = rsqrtf(var + 1e-5f);

        float g[8], bb[8];
        *(float4*)&g[0]  = *(const float4*)(ln_g + lane * 8);
        *(float4*)&g[4]  = *(const float4*)(ln_g + lane * 8 + 4);
        *(float4*)&bb[0] = *(const float4*)(ln_b + lane * 8);
        *(float4*)&bb[4] = *(const float4*)(ln_b + lane * 8 + 4);

        float sv[8];
#pragma unroll
        for (int i2 = 0; i2 < 8; ++i2) {
            float y = (x[i2] - mu) * rstd * g[i2] + bb[i2];
            sv[i2] = y / (1.f + expf(-y));
        }
        float rsum[4];
#pragma unroll
        for (int c = 0; c < 4; ++c) {
            const float* wr = w2 + c * 512 + lane * 8;
            float w[8];
            *(float4*)&w[0] = *(const float4*)wr;
            *(float4*)&w[4] = *(const float4*)(wr + 4);
            float p = 0.f;
#pragma unroll
            for (int i2 = 0; i2 < 8; ++i2) p += sv[i2] * w[i2];
            rsum[c] = p;
        }
        for (int m = 32; m; m >>= 1) {
            rsum[0] += __shfl_xor(rsum[0], m);
            rsum[1] += __shfl_xor(rsum[1], m);
            rsum[2] += __shfl_xor(rsum[2], m);
            rsum[3] += __shfl_xor(rsum[3], m);
        }
        if (lane == 0) {
            if (j == 0) {
                offs[0][0] = offs[0][1] = offs[0][2] = 0.f;
                size_t ob = (size_t)b * 24 * 3;
                out_off[ob] = 0.f; out_off[ob + 1] = 0.f; out_off[ob + 2] = 0.f;
            } else {
                float d0 = rsum[0] + b2[0], d1 = rsum[1] + b2[1], d2 = rsum[2] + b2[2];
                float lr = rsum[3] + b2[3];
                float nrm = sqrtf(d0 * d0 + d1 * d1 + d2 * d2);
                float inv = 1.f / fmaxf(nrm, 1e-6f);
                float L = (lr > 0.f) ? lr + log1pf(expf(-lr)) : log1pf(expf(lr));
                float o0 = d0 * inv * L, o1 = d1 * inv * L, o2 = d2 * inv * L;
                offs[j][0] = o0; offs[j][1] = o1; offs[j][2] = o2;
                size_t ob = ((size_t)b * 24 + j) * 3;
                out_off[ob] = o0; out_off[ob + 1] = o1; out_off[ob + 2] = o2;
                out_len[(size_t)b * 23 + j - 1] = L;
            }
        }
    }
    __syncthreads();
    if (tid < 3) {
        int d = tid;
        float cum[24]; cum[0] = 0.f;
        out_joints[(size_t)b * 24 * 3 + d] = 0.f;
        for (int j = 1; j < 24; ++j) {
            cum[j] = offs[j][d] + cum[parent[j]];
            out_joints[((size_t)b * 24 + j) * 3 + d] = cum[j];
        }
    }
}

// ---------- launch ----------
extern "C" void kernel_launch(void* const* d_in, const int* in_sizes, int n_in,
                              void* d_out, int out_size, void* d_ws, size_t ws_size,
                              hipStream_t stream) {
    const float* z    = (const float*)d_in[0];   // (1024,128,512)
    const float* jq   = (const float*)d_in[1];   // (1,24,512)
    const float* ipw  = (const float*)d_in[2];   // (1536,512)
    const float* ipb  = (const float*)d_in[3];   // (1536,)
    const float* opw  = (const float*)d_in[4];   // (512,512)
    const float* opb  = (const float*)d_in[5];
    const float* w1   = (const float*)d_in[6];   // (512,512)
    const float* b1   = (const float*)d_in[7];
    const float* lng  = (const float*)d_in[8];
    const float* lnb  = (const float*)d_in[9];
    const float* w2   = (const float*)d_in[10];  // (4,512)
    const float* b2   = (const float*)d_in[11];
    const int* parent = (const int*)d_in[12];
    float* out = (float*)d_out;

    char* ws = (char*)d_ws;
    size_t off = 0;
    auto alloc = [&](size_t bytes) {
        off = (off + 255) & ~(size_t)255;
        char* p = ws + off;
        off += bytes;
        return p;
    };

    // zb region (134.2 MB); after GEMM1 it is dead and re-used for ob (25.2 MB) + hm (50.3 MB)
    char*           zb_region = alloc((size_t)67108864 * 2);
    unsigned short* zb  = (unsigned short*)zb_region;
    unsigned short* ob  = (unsigned short*)zb_region;                 // alias, used post-GEMM1
    float*          hm  = (float*)(zb_region + 33554432);             // alias at +32MB
    unsigned short* scV = (unsigned short*)alloc((size_t)131072 * 704 * 2);  // 184.5 MB
    unsigned short* Bcat  = (unsigned short*)alloc((size_t)768 * 512 * 2);
    float*          bias1 = (float*)alloc(768 * 4);
    float*          qf    = (float*)alloc((size_t)24 * 512 * 4);
    unsigned short* opT   = (unsigned short*)alloc((size_t)512 * 512 * 2);
    unsigned short* w1b   = (unsigned short*)alloc((size_t)512 * 512 * 2);
    unsigned short* Wfold = (unsigned short*)alloc((size_t)512 * 512 * 2);
    float*          bfold = (float*)alloc(512 * 4);

    // --- prep: converts / folds (all tiny except z convert) ---
    cvt8_kernel<<<32768, 256, 0, stream>>>(z, zb, 8388608);                       // z -> bf16
    cvt8_kernel<<<128, 256, 0, stream>>>(ipw + (size_t)1024 * 512,
                                         Bcat + (size_t)192 * 512, 32768);        // wv -> Bcat rows 192..703
    cvt8_kernel<<<128, 256, 0, stream>>>(w1, w1b, 32768);
    qproj_kernel<<<24, 256, 0, stream>>>(jq, ipw, ipb, qf);
    qkfold_kernel<<<192, 256, 0, stream>>>(qf, ipw, ipb, Bcat, bias1);            // rows 0..191
    pad_kernel<<<128, 256, 0, stream>>>(Bcat, bias1, ipb);
    transp_kernel<<<512, 256, 0, stream>>>(opw, opT);
    bfold_kernel<<<2, 256, 0, stream>>>(w1, opb, b1, bfold);
    // Wfold = w1 @ opw  (512x512, bf16)
    gemm128<true><<<dim3(4, 4), 256, 0, stream>>>(w1b, opT, nullptr, Wfold, 512, 512, 512);

    // --- fused scores|V GEMM: scV = zb @ [qk; wv]^T + bias, M=131072, N=768(704 stored), K=512 ---
    gemm128<true><<<dim3(6, 1024), 256, 0, stream>>>(zb, Bcat, bias1, scV, 512, 704, 704);

    // --- softmax + attn@V -> o (bf16, 24576x512) ---
    attn_kernel<<<dim3(1024, 8), 256, 0, stream>>>(scV, ob);

    // --- h = o @ Wfold^T + bfold (fp32 out for LN), M=24576 ---
    gemm128<false><<<dim3(4, 192), 256, 0, stream>>>(ob, Wfold, bfold, hm, 512, 512, 512);

    // --- LN + SiLU + w2 + dir/len + kinematic chain ---
    head_kernel<<<1024, 256, 0, stream>>>(hm, lng, lnb, w2, b2, parent, out);
}

// Round 3
// 854.540 us; speedup vs baseline: 1.3142x; 1.1234x over previous
//
#include <hip/hip_runtime.h>
#include <stdint.h>

// ---------- types / helpers ----------
typedef __bf16 bf16x8 __attribute__((ext_vector_type(8)));
typedef float  f32x4  __attribute__((ext_vector_type(4)));

#define DEV __device__ __forceinline__

DEV unsigned short f2bf(float f) {
    unsigned int u = __float_as_uint(f);
    unsigned int r = (u + 0x7fffu + ((u >> 16) & 1u)) >> 16;   // RNE
    return (unsigned short)r;
}
DEV float bf2f(unsigned short s) {
    return __uint_as_float(((unsigned int)s) << 16);
}

typedef __attribute__((address_space(1))) const void gv_t;
typedef __attribute__((address_space(3))) void lv_t;
DEV void stage16(const unsigned short* g, unsigned short* l) {
    // async global->LDS DMA, 16B/lane, dest = wave-uniform base + lane*16
    __builtin_amdgcn_global_load_lds((gv_t*)g, (lv_t*)l, 16, 0, 0);
}

// ---------- vectorized fp32 -> bf16 (8 elements / thread) ----------
__global__ __launch_bounds__(256) void cvt8_kernel(const float* __restrict__ src,
                                                   unsigned short* __restrict__ dst, int n8) {
    int i = blockIdx.x * blockDim.x + threadIdx.x;
    if (i >= n8) return;
    const float4* s = (const float4*)(src + (size_t)i * 8);
    float4 x = s[0], y = s[1];
    uint4 pk; unsigned short* p = (unsigned short*)&pk;
    p[0]=f2bf(x.x); p[1]=f2bf(x.y); p[2]=f2bf(x.z); p[3]=f2bf(x.w);
    p[4]=f2bf(y.x); p[5]=f2bf(y.y); p[6]=f2bf(y.z); p[7]=f2bf(y.w);
    ((uint4*)dst)[i] = pk;
}

// ---------- q = joint_queries @ wq^T + bq  (24 x 512, batch-invariant) ----------
__global__ __launch_bounds__(256) void qproj_kernel(const float* __restrict__ jq,
                                                    const float* __restrict__ ipw,
                                                    const float* __restrict__ ipb,
                                                    float* __restrict__ q) {
    __shared__ float zq[512];
    int j = blockIdx.x, t = threadIdx.x;
    zq[t] = jq[j * 512 + t];
    zq[t + 256] = jq[j * 512 + t + 256];
    __syncthreads();
    for (int c = t; c < 512; c += 256) {
        float acc = ipb[c];
        const float* wr = ipw + (size_t)c * 512;
        for (int e = 0; e < 512; ++e) acc += zq[e] * wr[e];
        q[j * 512 + c] = acc;
    }
}

// ---------- qk_fold[hj][e] = (1/8) sum_d q[j][h*64+d]*wk[h*64+d][e] -> Bcat rows 0..191 ----------
__global__ __launch_bounds__(256) void qkfold_kernel(const float* __restrict__ q,
                                                     const float* __restrict__ ipw,
                                                     const float* __restrict__ ipb,
                                                     unsigned short* __restrict__ Bcat,
                                                     float* __restrict__ bias1) {
    int hj = blockIdx.x;                // hj = h*24 + j
    int h = hj / 24, j = hj - h * 24;
    int t = threadIdx.x;
    __shared__ float qh[64];
    if (t < 64) qh[t] = q[j * 512 + h * 64 + t];
    __syncthreads();
    for (int e = t; e < 512; e += 256) {
        float acc = 0.f;
        for (int d = 0; d < 64; ++d)
            acc += qh[d] * ipw[(size_t)(512 + h * 64 + d) * 512 + e];
        Bcat[(size_t)hj * 512 + e] = f2bf(acc * 0.125f);
    }
    if (t == 0) {
        float acc = 0.f;
        for (int d = 0; d < 64; ++d) acc += qh[d] * ipb[512 + h * 64 + d];
        bias1[hj] = acc * 0.125f;
    }
}

// ---------- pad: Bcat rows 704..767 = 0, bias1[192..767] ----------
__global__ __launch_bounds__(256) void pad_kernel(unsigned short* __restrict__ Bcat,
                                                  float* __restrict__ bias1,
                                                  const float* __restrict__ ipb) {
    int idx = blockIdx.x * 256 + threadIdx.x;
    if (idx < 32768) Bcat[(size_t)704 * 512 + idx] = 0;
    if (idx < 512) bias1[192 + idx] = ipb[1024 + idx];
    if (idx < 64) bias1[704 + idx] = 0.f;
}

// ---------- opT[j][k] = bf16(opw[k][j]) ----------
__global__ __launch_bounds__(256) void transp_kernel(const float* __restrict__ opw,
                                                     unsigned short* __restrict__ opT) {
    int j = blockIdx.x;
    for (int k = threadIdx.x; k < 512; k += 256)
        opT[(size_t)j * 512 + k] = f2bf(opw[(size_t)k * 512 + j]);
}

// ---------- bfold[i] = w1[i,:].opb + b1[i]  (fp32) ----------
__global__ __launch_bounds__(256) void bfold_kernel(const float* __restrict__ w1,
                                                    const float* __restrict__ opb,
                                                    const float* __restrict__ b1,
                                                    float* __restrict__ bfold) {
    __shared__ float ob[512];
    int t = threadIdx.x;
    ob[t] = opb[t]; ob[t + 256] = opb[t + 256];
    __syncthreads();
    int i = blockIdx.x * 256 + t;
    float acc = b1[i];
    const float* wr = w1 + (size_t)i * 512;
    for (int k = 0; k < 512; ++k) acc += wr[k] * ob[k];
    bfold[i] = acc;
}

// ---------- m97-structure GEMM: C(M,N)=A(M,K)@B(N,K)^T + bias, 128x128 tile, BK=32 ----------
template <bool CBF16>
__global__ __launch_bounds__(256) void gemm128(const unsigned short* __restrict__ A,
                                               const unsigned short* __restrict__ B,
                                               const float* __restrict__ bias,
                                               void* __restrict__ Cptr,
                                               int K, int ldc, int Nstore) {
    __shared__ unsigned short As[4096];   // 128 x 32, row-major, unpadded (global_load_lds contiguity)
    __shared__ unsigned short Bs[4096];

    const int tid = threadIdx.x, wv = tid >> 6, lane = tid & 63;
    const int m0 = blockIdx.y << 7, n0 = blockIdx.x << 7;
    const int wr = wv >> 1, wc = wv & 1;

    const int srow = lane >> 2;            // 0..15
    const int scol = (lane & 3) << 3;      // 0,8,16,24
    const int c0 = wv << 1;
    const unsigned short* pA = A + (size_t)(m0 + c0 * 16 + srow) * K + scol;
    const unsigned short* pB = B + (size_t)(n0 + c0 * 16 + srow) * K + scol;
    unsigned short* lA = As + (c0 << 9);
    unsigned short* lB = Bs + (c0 << 9);
    const size_t rowStep = (size_t)16 * K;

    f32x4 acc[4][4];
#pragma unroll
    for (int i = 0; i < 4; ++i)
#pragma unroll
        for (int j = 0; j < 4; ++j) acc[i][j] = f32x4{0.f, 0.f, 0.f, 0.f};

    const int row16 = lane & 15, kg8 = (lane >> 4) << 3;
    const int aoff = ((wr << 6) + row16) * 32 + kg8;
    const int boff = ((wc << 6) + row16) * 32 + kg8;

    for (int kb = 0; kb < K; kb += 32) {
        stage16(pA + kb, lA);
        stage16(pA + rowStep + kb, lA + 512);
        stage16(pB + kb, lB);
        stage16(pB + rowStep + kb, lB + 512);
        __syncthreads();

        bf16x8 a[4], b[4];
#pragma unroll
        for (int i = 0; i < 4; ++i) a[i] = *(const bf16x8*)&As[aoff + (i << 9)];
#pragma unroll
        for (int j = 0; j < 4; ++j) b[j] = *(const bf16x8*)&Bs[boff + (j << 9)];
#pragma unroll
        for (int i = 0; i < 4; ++i)
#pragma unroll
            for (int j = 0; j < 4; ++j)
                acc[i][j] = __builtin_amdgcn_mfma_f32_16x16x32_bf16(a[i], b[j], acc[i][j], 0, 0, 0);
        __syncthreads();
    }

    const int cg = lane >> 4, col = lane & 15;
#pragma unroll
    for (int j = 0; j < 4; ++j) {
        int gn = n0 + (wc << 6) + (j << 4) + col;
        if (gn >= Nstore) continue;
        float bv = bias ? bias[gn] : 0.f;
#pragma unroll
        for (int i = 0; i < 4; ++i) {
            int gmb = m0 + (wr << 6) + (i << 4) + (cg << 2);
#pragma unroll
            for (int rr = 0; rr < 4; ++rr) {
                float val = acc[i][j][rr] + bv;
                if constexpr (CBF16)
                    ((unsigned short*)Cptr)[(size_t)(gmb + rr) * ldc + gn] = f2bf(val);
                else
                    ((float*)Cptr)[(size_t)(gmb + rr) * ldc + gn] = val;
            }
        }
    }
}

// ---------- attention v2: MFMA-based softmax(P)@V per (head-pair, b) ----------
// Block = 256 threads / 4 waves; blockIdx.x = head pair hp (heads 2hp,2hp+1), blockIdx.y = b.
// pmat[h'][j][s]: P in MFMA A-layout (rows 24..31 zero). vt[h'][d][s]: V^T in B-layout.
// Wave w: h' = w>>1, n-half = w&1 (d-cols 32*nh..32*nh+31). 16 MFMAs per wave.
__global__ __launch_bounds__(256) void attn2_kernel(const unsigned short* __restrict__ scV,
                                                    unsigned short* __restrict__ o) {
    const int hp = blockIdx.x, b = blockIdx.y, tid = threadIdx.x;
    const int wv = tid >> 6, lane = tid & 63;
    __shared__ unsigned short pmat[2][32][136];   // +8 pad: 2-way banks (free)
    __shared__ unsigned short vt[2][64][136];

    // zero pad rows 24..31
    for (int idx = tid; idx < 2 * 8 * 136; idx += 256) {
        int h = idx / (8 * 136), rem = idx % (8 * 136);
        pmat[h][24 + rem / 136][rem % 136] = 0;
    }
    const size_t rowbase = (size_t)b * 128;
    // scores -> pmat[h'][j][s] (transpose; uint4 reads, coalesced)
    for (int idx = tid; idx < 768; idx += 256) {        // 2 heads x 128 s x 3 groups
        int h = idx / 384, rem = idx - h * 384;
        int s = rem / 3, g = rem - s * 3;
        uint4 v = *(const uint4*)&scV[(rowbase + s) * 704 + (hp * 2 + h) * 24 + g * 8];
        const unsigned short* pv = (const unsigned short*)&v;
#pragma unroll
        for (int u = 0; u < 8; ++u) pmat[h][g * 8 + u][s] = pv[u];
    }
    // V -> vt[h'][d][s] (transpose)
    for (int idx = tid; idx < 2048; idx += 256) {       // 2 heads x 128 s x 8 groups
        int h = idx >> 10, rem = idx & 1023;
        int s = rem >> 3, c = rem & 7;
        uint4 v = *(const uint4*)&scV[(rowbase + s) * 704 + 192 + (hp * 2 + h) * 64 + c * 8];
        const unsigned short* pv = (const unsigned short*)&v;
#pragma unroll
        for (int u = 0; u < 8; ++u) vt[h][c * 8 + u][s] = pv[u];
    }
    __syncthreads();

    // softmax in-place over pmat rows; wave w handles 12 of the 48 (h',j) rows
    for (int i = 0; i < 12; ++i) {
        int r = wv * 12 + i;
        int h = r / 24, j = r - h * 24;
        float x0 = bf2f(pmat[h][j][lane]);
        float x1 = bf2f(pmat[h][j][lane + 64]);
        float mx = fmaxf(x0, x1);
        for (int m = 32; m; m >>= 1) mx = fmaxf(mx, __shfl_xor(mx, m));
        float e0 = __expf(x0 - mx), e1 = __expf(x1 - mx);
        float sm = e0 + e1;
        for (int m = 32; m; m >>= 1) sm += __shfl_xor(sm, m);
        float inv = 1.f / sm;
        pmat[h][j][lane] = f2bf(e0 * inv);
        pmat[h][j][lane + 64] = f2bf(e1 * inv);
    }
    __syncthreads();

    // MFMA: P(32x128) @ V^T-layout(64x128) -> O(32x64), per head; wave does one 32-col half
    const int h = wv >> 1, nh = wv & 1;
    const int row16 = lane & 15, kg8 = (lane >> 4) << 3;
    f32x4 acc[2][2];
#pragma unroll
    for (int mt = 0; mt < 2; ++mt)
#pragma unroll
        for (int nt = 0; nt < 2; ++nt) acc[mt][nt] = f32x4{0.f, 0.f, 0.f, 0.f};

#pragma unroll
    for (int ks = 0; ks < 4; ++ks) {
        bf16x8 a0 = *(const bf16x8*)&pmat[h][row16][ks * 32 + kg8];
        bf16x8 a1 = *(const bf16x8*)&pmat[h][16 + row16][ks * 32 + kg8];
        bf16x8 b0 = *(const bf16x8*)&vt[h][nh * 32 + row16][ks * 32 + kg8];
        bf16x8 b1 = *(const bf16x8*)&vt[h][nh * 32 + 16 + row16][ks * 32 + kg8];
        acc[0][0] = __builtin_amdgcn_mfma_f32_16x16x32_bf16(a0, b0, acc[0][0], 0, 0, 0);
        acc[0][1] = __builtin_amdgcn_mfma_f32_16x16x32_bf16(a0, b1, acc[0][1], 0, 0, 0);
        acc[1][0] = __builtin_amdgcn_mfma_f32_16x16x32_bf16(a1, b0, acc[1][0], 0, 0, 0);
        acc[1][1] = __builtin_amdgcn_mfma_f32_16x16x32_bf16(a1, b1, acc[1][1], 0, 0, 0);
    }

    // epilogue: C/D layout col=lane&15, row=(lane>>4)*4+reg
    const int cg = lane >> 4, col = lane & 15;
    const int hg = hp * 2 + h;
#pragma unroll
    for (int mt = 0; mt < 2; ++mt)
#pragma unroll
        for (int rr = 0; rr < 4; ++rr) {
            int j = mt * 16 + cg * 4 + rr;
            if (j < 24)
#pragma unroll
                for (int nt = 0; nt < 2; ++nt) {
                    int d = hg * 64 + nh * 32 + nt * 16 + col;
                    o[((size_t)b * 24 + j) * 512 + d] = f2bf(acc[mt][nt][rr]);
                }
        }
}

// ---------- epilogue: LN + SiLU + w2 + normalize/softplus + kinematic chain ----------
__global__ __launch_bounds__(256) void head_kernel(const float* __restrict__ hmat,
                                                   const float* __restrict__ ln_g,
                                                   const float* __restrict__ ln_b,
                                                   const float* __restrict__ w2,
                                                   const float* __restrict__ b2,
                                                   const int* __restrict__ parent,
                                                   float* __restrict__ out) {
    const int b = blockIdx.x, tid = threadIdx.x, wv = tid >> 6, lane = tid & 63;
    __shared__ float offs[24][3];
    float* out_joints = out;
    float* out_off    = out + 73728;    // 1024*24*3
    float* out_len    = out + 147456;   // + 1024*24*3

    for (int batch = 0; batch < 6; ++batch) {
        int j = batch * 4 + wv;
        const float* hr = hmat + ((size_t)b * 24 + j) * 512 + lane * 8;
        float x[8];
        *(float4*)&x[0] = *(const float4*)hr;
        *(float4*)&x[4] = *(const float4*)(hr + 4);
        float s1 = 0.f, s2 = 0.f;
#pragma unroll
        for (int i2 = 0; i2 < 8; ++i2) { s1 += x[i2]; s2 += x[i2] * x[i2]; }
        for (int m = 32; m; m >>= 1) { s1 += __shfl_xor(s1, m); s2 += __shfl_xor(s2, m); }
        float mu   = s1 * (1.f / 512.f);
        float var  = s2 * (1.f / 512.f) - mu * mu;
        float rstd = rsqrtf(var + 1e-5f);

        float g[8], bb[8];
        *(float4*)&g[0]  = *(const float4*)(ln_g + lane * 8);
        *(float4*)&g[4]  = *(const float4*)(ln_g + lane * 8 + 4);
        *(float4*)&bb[0] = *(const float4*)(ln_b + lane * 8);
        *(float4*)&bb[4] = *(const float4*)(ln_b + lane * 8 + 4);

        float sv[8];
#pragma unroll
        for (int i2 = 0; i2 < 8; ++i2) {
            float y = (x[i2] - mu) * rstd * g[i2] + bb[i2];
            sv[i2] = y / (1.f + expf(-y));
        }
        float rsum[4];
#pragma unroll
        for (int c = 0; c < 4; ++c) {
            const float* wr = w2 + c * 512 + lane * 8;
            float w[8];
            *(float4*)&w[0] = *(const float4*)wr;
            *(float4*)&w[4] = *(const float4*)(wr + 4);
            float p = 0.f;
#pragma unroll
            for (int i2 = 0; i2 < 8; ++i2) p += sv[i2] * w[i2];
            rsum[c] = p;
        }
        for (int m = 32; m; m >>= 1) {
            rsum[0] += __shfl_xor(rsum[0], m);
            rsum[1] += __shfl_xor(rsum[1], m);
            rsum[2] += __shfl_xor(rsum[2], m);
            rsum[3] += __shfl_xor(rsum[3], m);
        }
        if (lane == 0) {
            if (j == 0) {
                offs[0][0] = offs[0][1] = offs[0][2] = 0.f;
                size_t ob = (size_t)b * 24 * 3;
                out_off[ob] = 0.f; out_off[ob + 1] = 0.f; out_off[ob + 2] = 0.f;
            } else {
                float d0 = rsum[0] + b2[0], d1 = rsum[1] + b2[1], d2 = rsum[2] + b2[2];
                float lr = rsum[3] + b2[3];
                float nrm = sqrtf(d0 * d0 + d1 * d1 + d2 * d2);
                float inv = 1.f / fmaxf(nrm, 1e-6f);
                float L = (lr > 0.f) ? lr + log1pf(expf(-lr)) : log1pf(expf(lr));
                float o0 = d0 * inv * L, o1 = d1 * inv * L, o2 = d2 * inv * L;
                offs[j][0] = o0; offs[j][1] = o1; offs[j][2] = o2;
                size_t ob = ((size_t)b * 24 + j) * 3;
                out_off[ob] = o0; out_off[ob + 1] = o1; out_off[ob + 2] = o2;
                out_len[(size_t)b * 23 + j - 1] = L;
            }
        }
    }
    __syncthreads();
    if (tid < 3) {
        int d = tid;
        float cum[24]; cum[0] = 0.f;
        out_joints[(size_t)b * 24 * 3 + d] = 0.f;
        for (int j = 1; j < 24; ++j) {
            cum[j] = offs[j][d] + cum[parent[j]];
            out_joints[((size_t)b * 24 + j) * 3 + d] = cum[j];
        }
    }
}

// ---------- launch ----------
extern "C" void kernel_launch(void* const* d_in, const int* in_sizes, int n_in,
                              void* d_out, int out_size, void* d_ws, size_t ws_size,
                              hipStream_t stream) {
    const float* z    = (const float*)d_in[0];   // (1024,128,512)
    const float* jq   = (const float*)d_in[1];   // (1,24,512)
    const float* ipw  = (const float*)d_in[2];   // (1536,512)
    const float* ipb  = (const float*)d_in[3];   // (1536,)
    const float* opw  = (const float*)d_in[4];   // (512,512)
    const float* opb  = (const float*)d_in[5];
    const float* w1   = (const float*)d_in[6];   // (512,512)
    const float* b1   = (const float*)d_in[7];
    const float* lng  = (const float*)d_in[8];
    const float* lnb  = (const float*)d_in[9];
    const float* w2   = (const float*)d_in[10];  // (4,512)
    const float* b2   = (const float*)d_in[11];
    const int* parent = (const int*)d_in[12];
    float* out = (float*)d_out;

    char* ws = (char*)d_ws;
    size_t off = 0;
    auto alloc = [&](size_t bytes) {
        off = (off + 255) & ~(size_t)255;
        char* p = ws + off;
        off += bytes;
        return p;
    };

    // zb region (134.2 MB); after GEMM1 it is dead and re-used for ob (25.2 MB) + hm (50.3 MB)
    char*           zb_region = alloc((size_t)67108864 * 2);
    unsigned short* zb  = (unsigned short*)zb_region;
    unsigned short* ob  = (unsigned short*)zb_region;                 // alias, used post-GEMM1
    float*          hm  = (float*)(zb_region + 33554432);             // alias at +32MB
    unsigned short* scV = (unsigned short*)alloc((size_t)131072 * 704 * 2);  // 184.5 MB
    unsigned short* Bcat  = (unsigned short*)alloc((size_t)768 * 512 * 2);
    float*          bias1 = (float*)alloc(768 * 4);
    float*          qf    = (float*)alloc((size_t)24 * 512 * 4);
    unsigned short* opT   = (unsigned short*)alloc((size_t)512 * 512 * 2);
    unsigned short* w1b   = (unsigned short*)alloc((size_t)512 * 512 * 2);
    unsigned short* Wfold = (unsigned short*)alloc((size_t)512 * 512 * 2);
    float*          bfold = (float*)alloc(512 * 4);

    // --- prep: converts / folds (all tiny except z convert) ---
    cvt8_kernel<<<32768, 256, 0, stream>>>(z, zb, 8388608);                       // z -> bf16
    cvt8_kernel<<<128, 256, 0, stream>>>(ipw + (size_t)1024 * 512,
                                         Bcat + (size_t)192 * 512, 32768);        // wv -> Bcat rows 192..703
    cvt8_kernel<<<128, 256, 0, stream>>>(w1, w1b, 32768);
    qproj_kernel<<<24, 256, 0, stream>>>(jq, ipw, ipb, qf);
    qkfold_kernel<<<192, 256, 0, stream>>>(qf, ipw, ipb, Bcat, bias1);            // rows 0..191
    pad_kernel<<<128, 256, 0, stream>>>(Bcat, bias1, ipb);
    transp_kernel<<<512, 256, 0, stream>>>(opw, opT);
    bfold_kernel<<<2, 256, 0, stream>>>(w1, opb, b1, bfold);
    // Wfold = w1 @ opw  (512x512, bf16)
    gemm128<true><<<dim3(4, 4), 256, 0, stream>>>(w1b, opT, nullptr, Wfold, 512, 512, 512);

    // --- fused scores|V GEMM: scV = zb @ [qk; wv]^T + bias, M=131072, N=768(704 stored), K=512 ---
    gemm128<true><<<dim3(6, 1024), 256, 0, stream>>>(zb, Bcat, bias1, scV, 512, 704, 704);

    // --- attention: MFMA softmax(P)@V -> o (bf16, 24576x512) ---
    attn2_kernel<<<dim3(4, 1024), 256, 0, stream>>>(scV, ob);

    // --- h = o @ Wfold^T + bfold (fp32 out for LN), M=24576 ---
    gemm128<false><<<dim3(4, 192), 256, 0, stream>>>(ob, Wfold, bfold, hm, 512, 512, 512);

    // --- LN + SiLU + w2 + dir/len + kinematic chain ---
    head_kernel<<<1024, 256, 0, stream>>>(hm, lng, lnb, w2, b2, parent, out);
}

// Round 4
// 809.582 us; speedup vs baseline: 1.3872x; 1.0555x over previous
//
#include <hip/hip_runtime.h>
#include <stdint.h>

// ---------- types / helpers ----------
typedef __bf16 bf16x8 __attribute__((ext_vector_type(8)));
typedef float  f32x4  __attribute__((ext_vector_type(4)));

#define DEV __device__ __forceinline__

DEV unsigned short f2bf(float f) {
    unsigned int u = __float_as_uint(f);
    unsigned int r = (u + 0x7fffu + ((u >> 16) & 1u)) >> 16;   // RNE
    return (unsigned short)r;
}
DEV float bf2f(unsigned short s) {
    return __uint_as_float(((unsigned int)s) << 16);
}

typedef __attribute__((address_space(1))) const void gv_t;
typedef __attribute__((address_space(3))) void lv_t;
DEV void stage16(const unsigned short* g, unsigned short* l) {
    // async global->LDS DMA, 16B/lane, LDS dest = wave-uniform base + lane*16
    __builtin_amdgcn_global_load_lds((gv_t*)g, (lv_t*)l, 16, 0, 0);
}

// ---------- vectorized fp32 -> bf16 (8 elements / thread) ----------
__global__ __launch_bounds__(256) void cvt8_kernel(const float* __restrict__ src,
                                                   unsigned short* __restrict__ dst, int n8) {
    int i = blockIdx.x * blockDim.x + threadIdx.x;
    if (i >= n8) return;
    const float4* s = (const float4*)(src + (size_t)i * 8);
    float4 x = s[0], y = s[1];
    uint4 pk; unsigned short* p = (unsigned short*)&pk;
    p[0]=f2bf(x.x); p[1]=f2bf(x.y); p[2]=f2bf(x.z); p[3]=f2bf(x.w);
    p[4]=f2bf(y.x); p[5]=f2bf(y.y); p[6]=f2bf(y.z); p[7]=f2bf(y.w);
    ((uint4*)dst)[i] = pk;
}

// ---------- q = joint_queries @ wq^T + bq  (coalesced wave-dot version) ----------
// grid (24, 4): block = (joint j, 128-column slice)
__global__ __launch_bounds__(256) void qproj2_kernel(const float* __restrict__ jq,
                                                     const float* __restrict__ ipw,
                                                     const float* __restrict__ ipb,
                                                     float* __restrict__ q) {
    __shared__ float zq[512];
    const int j = blockIdx.x, cq = blockIdx.y, t = threadIdx.x;
    zq[t] = jq[j * 512 + t];
    zq[t + 256] = jq[j * 512 + t + 256];
    __syncthreads();
    const int wv = t >> 6, lane = t & 63;
    for (int i = 0; i < 32; ++i) {
        int c = cq * 128 + wv * 32 + i;
        const float* wr = ipw + (size_t)c * 512 + lane * 8;
        float4 a = *(const float4*)wr;
        float4 bq = *(const float4*)(wr + 4);
        const float* zp = zq + lane * 8;
        float p = a.x*zp[0] + a.y*zp[1] + a.z*zp[2] + a.w*zp[3]
                + bq.x*zp[4] + bq.y*zp[5] + bq.z*zp[6] + bq.w*zp[7];
        for (int m = 32; m; m >>= 1) p += __shfl_xor(p, m);
        if (lane == 0) q[j * 512 + c] = p + ipb[c];
    }
}

// ---------- qk_fold[hj][e] = (1/8) sum_d q[j][h*64+d]*wk[h*64+d][e] -> Bcat rows 0..191 ----------
__global__ __launch_bounds__(256) void qkfold_kernel(const float* __restrict__ q,
                                                     const float* __restrict__ ipw,
                                                     const float* __restrict__ ipb,
                                                     unsigned short* __restrict__ Bcat,
                                                     float* __restrict__ bias1) {
    int hj = blockIdx.x;                // hj = h*24 + j
    int h = hj / 24, j = hj - h * 24;
    int t = threadIdx.x;
    __shared__ float qh[64];
    if (t < 64) qh[t] = q[j * 512 + h * 64 + t];
    __syncthreads();
    for (int e = t; e < 512; e += 256) {
        float acc = 0.f;
        for (int d = 0; d < 64; ++d)
            acc += qh[d] * ipw[(size_t)(512 + h * 64 + d) * 512 + e];
        Bcat[(size_t)hj * 512 + e] = f2bf(acc * 0.125f);
    }
    if (t == 0) {
        float acc = 0.f;
        for (int d = 0; d < 64; ++d) acc += qh[d] * ipb[512 + h * 64 + d];
        bias1[hj] = acc * 0.125f;
    }
}

// ---------- pad: Bcat rows 704..767 = 0, bias1[192..767] ----------
__global__ __launch_bounds__(256) void pad_kernel(unsigned short* __restrict__ Bcat,
                                                  float* __restrict__ bias1,
                                                  const float* __restrict__ ipb) {
    int idx = blockIdx.x * 256 + threadIdx.x;
    if (idx < 32768) Bcat[(size_t)704 * 512 + idx] = 0;
    if (idx < 512) bias1[192 + idx] = ipb[1024 + idx];
    if (idx < 64) bias1[704 + idx] = 0.f;
}

// ---------- opT[j][k] = bf16(opw[k][j]) ----------
__global__ __launch_bounds__(256) void transp_kernel(const float* __restrict__ opw,
                                                     unsigned short* __restrict__ opT) {
    int j = blockIdx.x;
    for (int k = threadIdx.x; k < 512; k += 256)
        opT[(size_t)j * 512 + k] = f2bf(opw[(size_t)k * 512 + j]);
}

// ---------- bfold[i] = w1[i,:].opb + b1[i]  (fp32) ----------
__global__ __launch_bounds__(256) void bfold_kernel(const float* __restrict__ w1,
                                                    const float* __restrict__ opb,
                                                    const float* __restrict__ b1,
                                                    float* __restrict__ bfold) {
    __shared__ float ob[512];
    int t = threadIdx.x;
    ob[t] = opb[t]; ob[t + 256] = opb[t + 256];
    __syncthreads();
    int i = blockIdx.x * 256 + t;
    float acc = b1[i];
    const float* wr = w1 + (size_t)i * 512;
    for (int k = 0; k < 512; ++k) acc += wr[k] * ob[k];
    bfold[i] = acc;
}

// ---------- gemm128: C(M,N)=A@B^T + bias, 128x128 tile, row-major C (for Wfold) ----------
__global__ __launch_bounds__(256) void gemm128(const unsigned short* __restrict__ A,
                                               const unsigned short* __restrict__ B,
                                               const float* __restrict__ bias,
                                               unsigned short* __restrict__ C,
                                               int K, int ldc) {
    __shared__ unsigned short As[4096];
    __shared__ unsigned short Bs[4096];
    const int tid = threadIdx.x, wv = tid >> 6, lane = tid & 63;
    const int m0 = blockIdx.y << 7, n0 = blockIdx.x << 7;
    const int wr = wv >> 1, wc = wv & 1;
    const int srow = lane >> 2, scol = (lane & 3) << 3;
    const int c0 = wv << 1;
    const unsigned short* pA = A + (size_t)(m0 + c0 * 16 + srow) * K + scol;
    const unsigned short* pB = B + (size_t)(n0 + c0 * 16 + srow) * K + scol;
    unsigned short* lA = As + (c0 << 9);
    unsigned short* lB = Bs + (c0 << 9);
    const size_t rowStep = (size_t)16 * K;

    f32x4 acc[4][4];
#pragma unroll
    for (int i = 0; i < 4; ++i)
#pragma unroll
        for (int j = 0; j < 4; ++j) acc[i][j] = f32x4{0.f, 0.f, 0.f, 0.f};

    const int row16 = lane & 15, kg8 = (lane >> 4) << 3;
    const int aoff = ((wr << 6) + row16) * 32 + kg8;
    const int boff = ((wc << 6) + row16) * 32 + kg8;

    for (int kb = 0; kb < K; kb += 32) {
        stage16(pA + kb, lA);
        stage16(pA + rowStep + kb, lA + 512);
        stage16(pB + kb, lB);
        stage16(pB + rowStep + kb, lB + 512);
        __syncthreads();
        bf16x8 a[4], b[4];
#pragma unroll
        for (int i = 0; i < 4; ++i) a[i] = *(const bf16x8*)&As[aoff + (i << 9)];
#pragma unroll
        for (int j = 0; j < 4; ++j) b[j] = *(const bf16x8*)&Bs[boff + (j << 9)];
#pragma unroll
        for (int i = 0; i < 4; ++i)
#pragma unroll
            for (int j = 0; j < 4; ++j)
                acc[i][j] = __builtin_amdgcn_mfma_f32_16x16x32_bf16(a[i], b[j], acc[i][j], 0, 0, 0);
        __syncthreads();
    }
    const int cg = lane >> 4, col = lane & 15;
#pragma unroll
    for (int j = 0; j < 4; ++j) {
        int gn = n0 + (wc << 6) + (j << 4) + col;
        float bv = bias ? bias[gn] : 0.f;
#pragma unroll
        for (int i = 0; i < 4; ++i) {
            int gmb = m0 + (wr << 6) + (i << 4) + (cg << 2);
#pragma unroll
            for (int rr = 0; rr < 4; ++rr)
                C[(size_t)(gmb + rr) * ldc + gn] = f2bf(acc[i][j][rr] + bv);
        }
    }
}

// ---------- gemm128T: fused scores|V GEMM, TRANSPOSED store C^T[n][m], XCD swizzle ----------
// C^T row n: n<192 -> scores row hj; n in [192,704) -> V^T row d=n-192. ldcT = M = 131072.
__global__ __launch_bounds__(256) void gemm128T(const unsigned short* __restrict__ A,
                                                const unsigned short* __restrict__ B,
                                                const float* __restrict__ bias,
                                                unsigned short* __restrict__ CT,
                                                int K, int ldcT, int Nstore) {
    __shared__ unsigned short As[4096];
    __shared__ unsigned short Bs[4096];
    const int tid = threadIdx.x, wv = tid >> 6, lane = tid & 63;
    // XCD swizzle: 8 XCDs round-robin on raw blockIdx; give each XCD a contiguous y range
    const int bid = blockIdx.x;
    const int xcd = bid & 7, idx = bid >> 3;      // 768 blocks per xcd
    const int ystrip = idx / 6, x = idx - ystrip * 6;
    const int m0 = (xcd * 128 + ystrip) << 7;     // y in [0,1024)
    const int n0 = x << 7;
    const int wr = wv >> 1, wc = wv & 1;
    const int srow = lane >> 2, scol = (lane & 3) << 3;
    const int c0 = wv << 1;
    const unsigned short* pA = A + (size_t)(m0 + c0 * 16 + srow) * K + scol;
    const unsigned short* pB = B + (size_t)(n0 + c0 * 16 + srow) * K + scol;
    unsigned short* lA = As + (c0 << 9);
    unsigned short* lB = Bs + (c0 << 9);
    const size_t rowStep = (size_t)16 * K;

    f32x4 acc[4][4];
#pragma unroll
    for (int i = 0; i < 4; ++i)
#pragma unroll
        for (int j = 0; j < 4; ++j) acc[i][j] = f32x4{0.f, 0.f, 0.f, 0.f};

    const int row16 = lane & 15, kg8 = (lane >> 4) << 3;
    const int aoff = ((wr << 6) + row16) * 32 + kg8;
    const int boff = ((wc << 6) + row16) * 32 + kg8;

    for (int kb = 0; kb < K; kb += 32) {
        stage16(pA + kb, lA);
        stage16(pA + rowStep + kb, lA + 512);
        stage16(pB + kb, lB);
        stage16(pB + rowStep + kb, lB + 512);
        __syncthreads();
        bf16x8 a[4], b[4];
#pragma unroll
        for (int i = 0; i < 4; ++i) a[i] = *(const bf16x8*)&As[aoff + (i << 9)];
#pragma unroll
        for (int j = 0; j < 4; ++j) b[j] = *(const bf16x8*)&Bs[boff + (j << 9)];
#pragma unroll
        for (int i = 0; i < 4; ++i)
#pragma unroll
            for (int j = 0; j < 4; ++j)
                acc[i][j] = __builtin_amdgcn_mfma_f32_16x16x32_bf16(a[i], b[j], acc[i][j], 0, 0, 0);
        __syncthreads();
    }
    // transposed store: CT[gn][gm..gm+3] as one 8B packed store
    const int cg = lane >> 4, col = lane & 15;
#pragma unroll
    for (int j = 0; j < 4; ++j) {
        int gn = n0 + (wc << 6) + (j << 4) + col;
        if (gn >= Nstore) continue;
        float bv = bias ? bias[gn] : 0.f;
        unsigned short* rowp = CT + (size_t)gn * ldcT;
#pragma unroll
        for (int i = 0; i < 4; ++i) {
            int gmb = m0 + (wr << 6) + (i << 4) + (cg << 2);
            ushort4 pk;
            pk.x = f2bf(acc[i][j][0] + bv);
            pk.y = f2bf(acc[i][j][1] + bv);
            pk.z = f2bf(acc[i][j][2] + bv);
            pk.w = f2bf(acc[i][j][3] + bv);
            *(ushort4*)(rowp + gmb) = pk;
        }
    }
}

// ---------- mega: per-b attention (softmax+PV) + Wfold GEMM + LN/SiLU/w2 + chain ----------
// block = b (1024 blocks, 256 threads). scTV rows contiguous in s -> DMA staging, no transpose.
__global__ __launch_bounds__(256) void mega_kernel(const unsigned short* __restrict__ scTV,
                                                   const unsigned short* __restrict__ Wfold,
                                                   const float* __restrict__ bfold,
                                                   const float* __restrict__ ln_g,
                                                   const float* __restrict__ ln_b,
                                                   const float* __restrict__ w2,
                                                   const float* __restrict__ b2,
                                                   const int* __restrict__ parent,
                                                   float* __restrict__ out) {
    const int b = blockIdx.x, tid = threadIdx.x;
    const int wv = tid >> 6, lane = tid & 63;
    const int row16 = lane & 15, kg8 = (lane >> 4) << 3;
    const int cg = lane >> 4, col = lane & 15;

    __shared__ unsigned short pmat[32 * 128];    // P (one head), rows 24..31 garbage (unused)
    __shared__ unsigned short vtB[16384];        // phase A: vt[64][128]; phase B: Bst[4][128*32]
    __shared__ unsigned short otile[32 * 520];   // o-tile, stride 520 (16B-aligned, 2-way banks)
    __shared__ float red1[32][4], red2[32][4];
    __shared__ float mus[32], rstds[32];
    __shared__ float dred[24][4][4];
    __shared__ float offs[24][3];

    const size_t colbase = (size_t)b * 128 + (size_t)(lane & 15) * 8;

    // ================= Phase A: attention =================
    for (int h = 0; h < 8; ++h) {
        if (wv < 3) {   // stage P rows: waves 0..2, 8 rows each (2 DMA instrs)
            const size_t r0 = (size_t)(h * 24 + 8 * wv + (lane >> 4));
            stage16(scTV + r0 * 131072 + colbase, pmat + (8 * wv) * 128);
            stage16(scTV + (r0 + 4) * 131072 + colbase, pmat + (8 * wv + 4) * 128);
        }
#pragma unroll
        for (int g = 0; g < 4; ++g) {   // stage V^T rows: each wave 16 rows
            const size_t r0 = (size_t)(192 + h * 64 + 16 * wv + 4 * g + (lane >> 4));
            stage16(scTV + r0 * 131072 + colbase, vtB + (16 * wv + 4 * g) * 128);
        }
        __syncthreads();

        // softmax over s (128) for rows wv*6 .. +6
        for (int i = 0; i < 6; ++i) {
            int j = wv * 6 + i;
            float x0 = bf2f(pmat[j * 128 + lane]);
            float x1 = bf2f(pmat[j * 128 + 64 + lane]);
            float mx = fmaxf(x0, x1);
            for (int m = 32; m; m >>= 1) mx = fmaxf(mx, __shfl_xor(mx, m));
            float e0 = __expf(x0 - mx), e1 = __expf(x1 - mx);
            float sm = e0 + e1;
            for (int m = 32; m; m >>= 1) sm += __shfl_xor(sm, m);
            float inv = 1.f / sm;
            pmat[j * 128 + lane] = f2bf(e0 * inv);
            pmat[j * 128 + 64 + lane] = f2bf(e1 * inv);
        }
        __syncthreads();

        // PV: wave handles d-cols [wv*16, wv*16+16)
        f32x4 pv0 = {0.f,0.f,0.f,0.f}, pv1 = {0.f,0.f,0.f,0.f};
#pragma unroll
        for (int ks = 0; ks < 4; ++ks) {
            bf16x8 a0 = *(const bf16x8*)&pmat[row16 * 128 + ks * 32 + kg8];
            bf16x8 a1 = *(const bf16x8*)&pmat[(16 + row16) * 128 + ks * 32 + kg8];
            bf16x8 bf = *(const bf16x8*)&vtB[(wv * 16 + row16) * 128 + ks * 32 + kg8];
            pv0 = __builtin_amdgcn_mfma_f32_16x16x32_bf16(a0, bf, pv0, 0, 0, 0);
            pv1 = __builtin_amdgcn_mfma_f32_16x16x32_bf16(a1, bf, pv1, 0, 0, 0);
        }
#pragma unroll
        for (int rr = 0; rr < 4; ++rr) {
            int j0 = cg * 4 + rr;
            otile[j0 * 520 + h * 64 + wv * 16 + col] = f2bf(pv0[rr]);
            int j1 = 16 + cg * 4 + rr;
            if (j1 < 24)
                otile[j1 * 520 + h * 64 + wv * 16 + col] = f2bf(pv1[rr]);
        }
        __syncthreads();
    }

    // ================= Phase B: h = otile @ Wfold^T + bfold =================
    const int ns = wv << 7;                      // wave's 128-col slice
    unsigned short* Bst = vtB + (wv << 12);      // 8 KB per wave

    f32x4 acc[2][8];
#pragma unroll
    for (int mt = 0; mt < 2; ++mt)
#pragma unroll
        for (int nt = 0; nt < 8; ++nt) acc[mt][nt] = f32x4{0.f,0.f,0.f,0.f};

    for (int kb = 0; kb < 512; kb += 32) {
#pragma unroll
        for (int g = 0; g < 8; ++g)
            stage16(Wfold + (size_t)(ns + 16 * g + (lane >> 2)) * 512 + kb + (lane & 3) * 8,
                    Bst + 16 * g * 32);
        __syncthreads();
        bf16x8 a0 = *(const bf16x8*)&otile[row16 * 520 + kb + kg8];
        bf16x8 a1 = *(const bf16x8*)&otile[(16 + row16) * 520 + kb + kg8];
#pragma unroll
        for (int nt = 0; nt < 8; ++nt) {
            bf16x8 bf = *(const bf16x8*)&Bst[(nt * 16 + row16) * 32 + kg8];
            acc[0][nt] = __builtin_amdgcn_mfma_f32_16x16x32_bf16(a0, bf, acc[0][nt], 0, 0, 0);
            acc[1][nt] = __builtin_amdgcn_mfma_f32_16x16x32_bf16(a1, bf, acc[1][nt], 0, 0, 0);
        }
        __syncthreads();
    }

    // bias + LN stats (per-row partial sums, 16-lane groups then cross-wave via LDS)
    int gcol[8]; float bvv[8];
#pragma unroll
    for (int nt = 0; nt < 8; ++nt) { gcol[nt] = ns + nt * 16 + col; bvv[nt] = bfold[gcol[nt]]; }
#pragma unroll
    for (int mt = 0; mt < 2; ++mt)
#pragma unroll
        for (int nt = 0; nt < 8; ++nt)
#pragma unroll
            for (int rr = 0; rr < 4; ++rr) acc[mt][nt][rr] += bvv[nt];

#pragma unroll
    for (int mt = 0; mt < 2; ++mt)
#pragma unroll
        for (int rr = 0; rr < 4; ++rr) {
            float s1 = 0.f, s2 = 0.f;
#pragma unroll
            for (int nt = 0; nt < 8; ++nt) { float v = acc[mt][nt][rr]; s1 += v; s2 += v * v; }
            s1 += __shfl_xor(s1, 1); s2 += __shfl_xor(s2, 1);
            s1 += __shfl_xor(s1, 2); s2 += __shfl_xor(s2, 2);
            s1 += __shfl_xor(s1, 4); s2 += __shfl_xor(s2, 4);
            s1 += __shfl_xor(s1, 8); s2 += __shfl_xor(s2, 8);
            if (col == 0) { int r = mt * 16 + cg * 4 + rr; red1[r][wv] = s1; red2[r][wv] = s2; }
        }
    __syncthreads();
    if (tid < 32) {
        float s1 = red1[tid][0] + red1[tid][1] + red1[tid][2] + red1[tid][3];
        float s2 = red2[tid][0] + red2[tid][1] + red2[tid][2] + red2[tid][3];
        float mu = s1 * (1.f / 512.f);
        float var = s2 * (1.f / 512.f) - mu * mu;
        mus[tid] = mu; rstds[tid] = rsqrtf(var + 1e-5f);
    }
    __syncthreads();

    // LN + SiLU + w2 partial dots
    float gg[8], bb[8], w2v[4][8];
#pragma unroll
    for (int nt = 0; nt < 8; ++nt) { gg[nt] = ln_g[gcol[nt]]; bb[nt] = ln_b[gcol[nt]]; }
#pragma unroll
    for (int c = 0; c < 4; ++c)
#pragma unroll
        for (int nt = 0; nt < 8; ++nt) w2v[c][nt] = w2[c * 512 + gcol[nt]];

#pragma unroll
    for (int mt = 0; mt < 2; ++mt)
#pragma unroll
        for (int rr = 0; rr < 4; ++rr) {
            int r = mt * 16 + cg * 4 + rr;
            float mu = mus[r], rs = rstds[r];
            float d0 = 0.f, d1 = 0.f, d2 = 0.f, d3 = 0.f;
#pragma unroll
            for (int nt = 0; nt < 8; ++nt) {
                float y = (acc[mt][nt][rr] - mu) * rs * gg[nt] + bb[nt];
                float sv = y / (1.f + __expf(-y));
                d0 += sv * w2v[0][nt]; d1 += sv * w2v[1][nt];
                d2 += sv * w2v[2][nt]; d3 += sv * w2v[3][nt];
            }
            d0 += __shfl_xor(d0, 1); d1 += __shfl_xor(d1, 1); d2 += __shfl_xor(d2, 1); d3 += __shfl_xor(d3, 1);
            d0 += __shfl_xor(d0, 2); d1 += __shfl_xor(d1, 2); d2 += __shfl_xor(d2, 2); d3 += __shfl_xor(d3, 2);
            d0 += __shfl_xor(d0, 4); d1 += __shfl_xor(d1, 4); d2 += __shfl_xor(d2, 4); d3 += __shfl_xor(d3, 4);
            d0 += __shfl_xor(d0, 8); d1 += __shfl_xor(d1, 8); d2 += __shfl_xor(d2, 8); d3 += __shfl_xor(d3, 8);
            if (col == 0 && r < 24) {
                dred[r][wv][0] = d0; dred[r][wv][1] = d1;
                dred[r][wv][2] = d2; dred[r][wv][3] = d3;
            }
        }
    __syncthreads();

    float* out_joints = out;
    float* out_off    = out + 73728;
    float* out_len    = out + 147456;
    if (tid < 24) {
        int j = tid;
        float rv[4];
#pragma unroll
        for (int c = 0; c < 4; ++c)
            rv[c] = dred[j][0][c] + dred[j][1][c] + dred[j][2][c] + dred[j][3][c] + b2[c];
        size_t ob = ((size_t)b * 24 + j) * 3;
        if (j == 0) {
            offs[0][0] = offs[0][1] = offs[0][2] = 0.f;
            out_off[ob] = 0.f; out_off[ob + 1] = 0.f; out_off[ob + 2] = 0.f;
        } else {
            float nrm = sqrtf(rv[0]*rv[0] + rv[1]*rv[1] + rv[2]*rv[2]);
            float inv = 1.f / fmaxf(nrm, 1e-6f);
            float lr = rv[3];
            float L = (lr > 0.f) ? lr + log1pf(expf(-lr)) : log1pf(expf(lr));
            float o0 = rv[0]*inv*L, o1 = rv[1]*inv*L, o2 = rv[2]*inv*L;
            offs[j][0] = o0; offs[j][1] = o1; offs[j][2] = o2;
            out_off[ob] = o0; out_off[ob + 1] = o1; out_off[ob + 2] = o2;
            out_len[(size_t)b * 23 + j - 1] = L;
        }
    }
    __syncthreads();
    if (tid < 3) {
        int d = tid;
        float cum[24]; cum[0] = 0.f;
        out_joints[(size_t)b * 24 * 3 + d] = 0.f;
        for (int j = 1; j < 24; ++j) {
            cum[j] = offs[j][d] + cum[parent[j]];
            out_joints[((size_t)b * 24 + j) * 3 + d] = cum[j];
        }
    }
}

// ---------- launch ----------
extern "C" void kernel_launch(void* const* d_in, const int* in_sizes, int n_in,
                              void* d_out, int out_size, void* d_ws, size_t ws_size,
                              hipStream_t stream) {
    const float* z    = (const float*)d_in[0];   // (1024,128,512)
    const float* jq   = (const float*)d_in[1];   // (1,24,512)
    const float* ipw  = (const float*)d_in[2];   // (1536,512)
    const float* ipb  = (const float*)d_in[3];   // (1536,)
    const float* opw  = (const float*)d_in[4];   // (512,512)
    const float* opb  = (const float*)d_in[5];
    const float* w1   = (const float*)d_in[6];   // (512,512)
    const float* b1   = (const float*)d_in[7];
    const float* lng  = (const float*)d_in[8];
    const float* lnb  = (const float*)d_in[9];
    const float* w2   = (const float*)d_in[10];  // (4,512)
    const float* b2   = (const float*)d_in[11];
    const int* parent = (const int*)d_in[12];
    float* out = (float*)d_out;

    char* ws = (char*)d_ws;
    size_t off = 0;
    auto alloc = [&](size_t bytes) {
        off = (off + 255) & ~(size_t)255;
        char* p = ws + off;
        off += bytes;
        return p;
    };

    unsigned short* zb    = (unsigned short*)alloc((size_t)67108864 * 2);        // 134 MB
    unsigned short* scTV  = (unsigned short*)alloc((size_t)704 * 131072 * 2);    // 184.5 MB
    unsigned short* Bcat  = (unsigned short*)alloc((size_t)768 * 512 * 2);
    float*          bias1 = (float*)alloc(768 * 4);
    float*          qf    = (float*)alloc((size_t)24 * 512 * 4);
    unsigned short* opT   = (unsigned short*)alloc((size_t)512 * 512 * 2);
    unsigned short* w1b   = (unsigned short*)alloc((size_t)512 * 512 * 2);
    unsigned short* Wfold = (unsigned short*)alloc((size_t)512 * 512 * 2);
    float*          bfold = (float*)alloc(512 * 4);

    // --- prep ---
    cvt8_kernel<<<32768, 256, 0, stream>>>(z, zb, 8388608);                       // z -> bf16
    cvt8_kernel<<<128, 256, 0, stream>>>(ipw + (size_t)1024 * 512,
                                         Bcat + (size_t)192 * 512, 32768);        // wv rows 192..703
    cvt8_kernel<<<128, 256, 0, stream>>>(w1, w1b, 32768);
    qproj2_kernel<<<dim3(24, 4), 256, 0, stream>>>(jq, ipw, ipb, qf);
    qkfold_kernel<<<192, 256, 0, stream>>>(qf, ipw, ipb, Bcat, bias1);            // rows 0..191
    pad_kernel<<<128, 256, 0, stream>>>(Bcat, bias1, ipb);
    transp_kernel<<<512, 256, 0, stream>>>(opw, opT);
    bfold_kernel<<<2, 256, 0, stream>>>(w1, opb, b1, bfold);
    gemm128<<<dim3(4, 4), 256, 0, stream>>>(w1b, opT, nullptr, Wfold, 512, 512);  // Wfold = w1@opw

    // --- fused scores|V GEMM, transposed store, XCD-swizzled 1D grid ---
    gemm128T<<<6144, 256, 0, stream>>>(zb, Bcat, bias1, scTV, 512, 131072, 704);

    // --- per-b mega: attention + Wfold GEMM + LN/SiLU/w2 + chain ---
    mega_kernel<<<1024, 256, 0, stream>>>(scTV, Wfold, bfold, lng, lnb, w2, b2, parent, out);
}